// Round 1
// baseline (405.723 us; speedup 1.0000x reference)
//
#include <hip/hip_runtime.h>
#include <hip/hip_bf16.h>

// ---------------------------------------------------------------------------
// DiffusionModule: AttentionPairBias + ConditionedFeedForward (AF3-style)
// B=1, N=1024, DS=768, DP=128, H=16, DH=48, DFF=1536. f32 in/out, bf16 MFMA.
// ---------------------------------------------------------------------------

typedef __attribute__((ext_vector_type(8))) short bf16x8;
typedef __attribute__((ext_vector_type(4))) float f32x4;

#define DEVFN static __device__ __forceinline__

DEVFN float bf2f(unsigned short u){
  union { unsigned int u; float f; } v; v.u = ((unsigned int)u) << 16; return v.f;
}
DEVFN unsigned short f2bf(float f){
  union { float f; unsigned int u; } v; v.f = f;
  unsigned int r = v.u + 0x7fffu + ((v.u >> 16) & 1u);
  return (unsigned short)(r >> 16);
}
DEVFN float sigf(float x){ return 1.f / (1.f + __expf(-x)); }

// ---------------- workspace layout (bytes) ----------------
#define OFF_SN    0x0000000ULL  // [1024][768] bf16  LN(single_cond)
#define OFF_SC    0x0180000ULL  // [1024][768] bf16  raw single_cond
#define OFF_XA    0x0300000ULL  // [1024][768] f32   LN(x)
#define OFF_W1    0x0600000ULL  // [3072][768] bf16  [ag|ab|fg|fb]^T
#define OFF_W2    0x0A80000ULL  // [1536][768] bf16  [attn_gate|ff_gate]^T
#define OFF_W3    0x0CC0000ULL  // [3072][768] bf16  [wq|wk|wv|wg]^T
#define OFF_W4    0x1140000ULL  // [3072][768] bf16  [ff_w1|ff_w2]^T
#define OFF_W5    0x15C0000ULL  // [768][1536] bf16  ff_w3^T
#define OFF_W6    0x1800000ULL  // [768][768]  bf16  wo^T
#define OFF_BIAS1 0x1920000ULL  // [3072] f32
#define OFF_BIASG 0x1923000ULL  // [1536] f32
#define OFF_BIASQ 0x1924800ULL  // [3072] f32
#define OFF_G1    0x1930000ULL  // [1024][3072] f32  sn @ [ag|ab|fg|fb]
#define OFF_GATES 0x2530000ULL  // [1024][1536] f32  sigmoid(sc@gate_w + b)
#define OFF_A     0x2B30000ULL  // [1024][768] bf16  adaLN out (attn)
#define OFF_F     0x2CB0000ULL  // [1024][768] bf16  adaLN out (ff)
#define OFF_QKVG  0x2E30000ULL  // [1024][3072] bf16
#define OFF_H12   0x3430000ULL  // [1024][3072] f32  f@[w1|w2]
#define OFF_HH    0x4030000ULL  // [1024][1536] bf16 silu(h1)*h2
#define OFF_GO    0x4330000ULL  // [1024][768] bf16  sigmoid(g)*o
#define OFF_AP    0x44B0000ULL  // [1024][768] f32   gated attn out
#define OFF_PB    0x47B0000ULL  // [16][1024][1024] bf16 pair bias

// ---------------- weight transpose+cast:  dst[n][k] = (bf16)src[k][n] -------
struct WJobs {
  const float* src[14];
  unsigned long long dst[14];
  int K[14];
  int N[14];
};

__global__ __launch_bounds__(256) void transpose_cast_kernel(WJobs jobs, char* ws){
  const int z = blockIdx.z;
  const int n0 = blockIdx.x * 32, k0 = blockIdx.y * 32;
  const int K = jobs.K[z], N = jobs.N[z];
  if(n0 >= N || k0 >= K) return;
  __shared__ float t[32][33];
  const int tx = threadIdx.x, ty = threadIdx.y; // 32 x 8
  const float* src = jobs.src[z];
  #pragma unroll
  for(int i=0;i<4;i++)
    t[ty + i*8][tx] = src[(long long)(k0 + ty + i*8) * N + n0 + tx];
  __syncthreads();
  unsigned short* dst = (unsigned short*)(ws + jobs.dst[z]);
  #pragma unroll
  for(int i=0;i<4;i++)
    dst[(long long)(n0 + ty + i*8) * K + k0 + tx] = f2bf(t[tx][ty + i*8]);
}

// ---------------- bias concat vectors ----------------
__global__ void build_bias_kernel(const float* agb, const float* bq,
                                  const float* gtb, const float* fgtb,
                                  const float* fgb,
                                  float* bias1, float* biasg, float* biasq){
  int t = blockIdx.x * 256 + threadIdx.x;
  if(t < 3072){
    float v = 0.f;
    if(t < 768) v = agb[t];
    else if(t >= 1536 && t < 2304) v = fgb[t - 1536];
    bias1[t] = v;
    biasq[t] = (t < 768) ? bq[t] : 0.f;
    if(t < 1536) biasg[t] = (t < 768) ? gtb[t] : fgtb[t - 768];
  }
}

// ---------------- row LayerNorm for x and single_cond ----------------
__global__ __launch_bounds__(256) void ln_kernel(const float* __restrict__ x,
    const float* __restrict__ sc, unsigned short* __restrict__ sn_bf,
    unsigned short* __restrict__ sc_bf, float* __restrict__ xa){
  const int row = blockIdx.x, t = threadIdx.x;
  const float* xr = x + (long long)row * 768;
  const float* sr = sc + (long long)row * 768;
  float xs[3], ss[3];
  float s0=0.f, s1=0.f, s2=0.f, s3=0.f;
  #pragma unroll
  for(int i=0;i<3;i++){
    float xv = xr[t + i*256], sv = sr[t + i*256];
    xs[i]=xv; ss[i]=sv;
    s0 += xv; s1 += xv*xv; s2 += sv; s3 += sv*sv;
  }
  #pragma unroll
  for(int o=32;o;o>>=1){
    s0 += __shfl_xor(s0,o); s1 += __shfl_xor(s1,o);
    s2 += __shfl_xor(s2,o); s3 += __shfl_xor(s3,o);
  }
  __shared__ float red[4][4];
  const int w = t >> 6;
  if((t & 63) == 0){ red[0][w]=s0; red[1][w]=s1; red[2][w]=s2; red[3][w]=s3; }
  __syncthreads();
  float tx0 = red[0][0]+red[0][1]+red[0][2]+red[0][3];
  float tx1 = red[1][0]+red[1][1]+red[1][2]+red[1][3];
  float ts0 = red[2][0]+red[2][1]+red[2][2]+red[2][3];
  float ts1 = red[3][0]+red[3][1]+red[3][2]+red[3][3];
  const float inv = 1.f/768.f;
  float mx = tx0*inv, vx = tx1*inv - mx*mx;
  float ms = ts0*inv, vs = ts1*inv - ms*ms;
  float rsx = rsqrtf(vx + 1e-5f), rss = rsqrtf(vs + 1e-5f);
  #pragma unroll
  for(int i=0;i<3;i++){
    int c = t + i*256;
    xa[(long long)row*768 + c]    = (xs[i]-mx)*rsx;
    sn_bf[(long long)row*768 + c] = f2bf((ss[i]-ms)*rss);
    sc_bf[(long long)row*768 + c] = f2bf(ss[i]);
  }
}

// ---------------- pair bias: pb[h][i][j] = LN(pair[i,j,:]) . wb[:,h] -------
// block: 64 consecutive (i,j) rows; 8 lanes per row (coalesced 128B lines).
__global__ __launch_bounds__(256) void pair_bias_kernel(
    const float* __restrict__ pair, const float* __restrict__ wb,
    unsigned short* __restrict__ pb){
  __shared__ float sWb[128][17];
  __shared__ float sOut[64][17];
  const int tid = threadIdx.x;
  for(int t = tid; t < 2048; t += 256) sWb[t >> 4][t & 15] = wb[t];
  __syncthreads();
  const int i  = blockIdx.x >> 4;
  const int j0 = (blockIdx.x & 15) << 6;
  const int w = tid >> 6, l = tid & 63, g = l >> 3, l8 = l & 7;
  #pragma unroll
  for(int it=0; it<2; it++){
    const int rl = it*32 + w*8 + g;          // local row 0..63
    const int j  = j0 + rl;
    const float4* pr = (const float4*)(pair + ((long long)(i << 10) + j) * 128);
    float vals[16];
    #pragma unroll
    for(int q=0;q<4;q++){
      float4 tv = pr[l8 + q*8];
      vals[q*4+0]=tv.x; vals[q*4+1]=tv.y; vals[q*4+2]=tv.z; vals[q*4+3]=tv.w;
    }
    float s=0.f, s2=0.f;
    #pragma unroll
    for(int e=0;e<16;e++){ s += vals[e]; s2 += vals[e]*vals[e]; }
    #pragma unroll
    for(int o=1;o<8;o<<=1){ s += __shfl_xor(s,o); s2 += __shfl_xor(s2,o); }
    const float m = s * (1.f/128.f);
    const float rs = rsqrtf(s2*(1.f/128.f) - m*m + 1e-5f);
    float a[16];
    #pragma unroll
    for(int h=0;h<16;h++) a[h]=0.f;
    #pragma unroll
    for(int q=0;q<4;q++){
      const int pbase = (l8 + q*8)*4;
      #pragma unroll
      for(int c2=0;c2<4;c2++){
        float nv = (vals[q*4+c2] - m) * rs;
        #pragma unroll
        for(int h=0;h<16;h++) a[h] += nv * sWb[pbase + c2][h];
      }
    }
    #pragma unroll
    for(int o=1;o<8;o<<=1)
      #pragma unroll
      for(int h=0;h<16;h++) a[h] += __shfl_xor(a[h], o);
    if(l8 == 0){
      #pragma unroll
      for(int h=0;h<16;h++) sOut[rl][h] = a[h];
    }
  }
  __syncthreads();
  {
    const int h = tid >> 4, jq = tid & 15;
    unsigned long long pk = 0;
    #pragma unroll
    for(int c2=0;c2<4;c2++)
      pk |= ((unsigned long long)f2bf(sOut[jq*4 + c2][h])) << (16*c2);
    *(unsigned long long*)&pb[((long long)h << 20) + ((long long)i << 10) + j0 + jq*4] = pk;
  }
}

// ---------------- generic MFMA GEMM:  C[M][N] = A[M][K] @ Bt[N][K]^T -------
// BM=64, BN=128, BK=32; 4 waves, wave w owns cols [w*32, w*32+32).
// EPI: 0 = f32 (+bias)   1 = sigmoid(v+bias) f32   2 = bf16(v+bias)
//      3 = gates*v f32   4 = ex0 + ex1 + gates*v f32
template<int EPI>
__global__ __launch_bounds__(256) void gemm_kernel(
    const unsigned short* __restrict__ A, const unsigned short* __restrict__ Bt,
    int M, int N, int K,
    const float* __restrict__ bias,
    float* __restrict__ Cf, unsigned short* __restrict__ Cb,
    const float* __restrict__ ex0, const float* __restrict__ ex1,
    const float* __restrict__ gates, int gate_off){
  __shared__ unsigned short sA[64][48];
  __shared__ unsigned short sB[128][48];
  const int m0 = blockIdx.x * 64, n0 = blockIdx.y * 128;
  const int tid = threadIdx.x;
  const int w = tid >> 6, l = tid & 63, l15 = l & 15, l4 = l >> 4;
  f32x4 zf = {0.f,0.f,0.f,0.f};
  f32x4 acc[4][2];
  #pragma unroll
  for(int m=0;m<4;m++)
    #pragma unroll
    for(int n=0;n<2;n++) acc[m][n] = zf;

  const int ra = tid >> 2, ka = (tid & 3) * 8;
  for(int k0 = 0; k0 < K; k0 += 32){
    *(bf16x8*)&sA[ra][ka]      = *(const bf16x8*)&A [(long long)(m0 + ra)      * K + k0 + ka];
    *(bf16x8*)&sB[ra][ka]      = *(const bf16x8*)&Bt[(long long)(n0 + ra)      * K + k0 + ka];
    *(bf16x8*)&sB[64 + ra][ka] = *(const bf16x8*)&Bt[(long long)(n0 + 64 + ra) * K + k0 + ka];
    __syncthreads();
    bf16x8 af[4], bg[2];
    #pragma unroll
    for(int m=0;m<4;m++) af[m] = *(const bf16x8*)&sA[m*16 + l15][l4*8];
    #pragma unroll
    for(int n=0;n<2;n++) bg[n] = *(const bf16x8*)&sB[w*32 + n*16 + l15][l4*8];
    #pragma unroll
    for(int m=0;m<4;m++)
      #pragma unroll
      for(int n=0;n<2;n++)
        acc[m][n] = __builtin_amdgcn_mfma_f32_16x16x32_bf16(af[m], bg[n], acc[m][n], 0, 0, 0);
    __syncthreads();
  }
  #pragma unroll
  for(int m=0;m<4;m++){
    #pragma unroll
    for(int n=0;n<2;n++){
      #pragma unroll
      for(int r=0;r<4;r++){
        const int i = m0 + m*16 + l4*4 + r;
        const int c = n0 + w*32 + n*16 + l15;
        float v = acc[m][n][r];
        if(EPI == 0){
          if(bias) v += bias[c];
          Cf[(long long)i*N + c] = v;
        } else if(EPI == 1){
          Cf[(long long)i*N + c] = sigf(v + bias[c]);
        } else if(EPI == 2){
          Cb[(long long)i*N + c] = f2bf(v + bias[c]);
        } else if(EPI == 3){
          Cf[(long long)i*N + c] = gates[(long long)i*1536 + gate_off + c] * v;
        } else {
          Cf[(long long)i*N + c] = ex0[(long long)i*N + c] + ex1[(long long)i*N + c]
                                 + gates[(long long)i*1536 + gate_off + c] * v;
        }
      }
    }
  }
}

// ---------------- elementwise: adaLN combine ----------------
__global__ __launch_bounds__(256) void ew1_kernel(const float* __restrict__ g1,
    const float* __restrict__ xa, unsigned short* __restrict__ a_bf,
    unsigned short* __restrict__ f_bf){
  const int i = blockIdx.x;
  const int c = blockIdx.y * 256 + threadIdx.x;
  const float* row = g1 + (long long)i * 3072;
  float xv = xa[(long long)i*768 + c];
  a_bf[(long long)i*768 + c] = f2bf(sigf(row[c])      * xv + row[768 + c]);
  f_bf[(long long)i*768 + c] = f2bf(sigf(row[1536+c]) * xv + row[2304 + c]);
}

// ---------------- elementwise: SwiGLU ----------------
__global__ __launch_bounds__(256) void ew2_kernel(const float* __restrict__ h12,
    unsigned short* __restrict__ hh){
  const int i = blockIdx.x;
  const int c = blockIdx.y * 256 + threadIdx.x;
  float h1 = h12[(long long)i*3072 + c];
  float h2 = h12[(long long)i*3072 + 1536 + c];
  hh[(long long)i*1536 + c] = f2bf((h1 * sigf(h1)) * h2);
}

// ---------------- attention: per (head, 16-row tile) ----------------
// 4 waves; wave w owns j in [w*256, w*256+256). QK via MFMA from global,
// wave softmax, PV via MFMA with per-wave LDS-transposed V chunks.
__global__ __launch_bounds__(256) void attn_kernel(
    const unsigned short* __restrict__ qkvg,
    const unsigned short* __restrict__ pbias,
    unsigned short* __restrict__ go){
  const int h  = blockIdx.x >> 6;
  const int i0 = (blockIdx.x & 63) << 4;
  const int tid = threadIdx.x;
  const int w = tid >> 6, l = tid & 63, l15 = l & 15, l4 = l >> 4;

  __shared__ unsigned short sP[16][1032];
  __shared__ float sRedM[16][4];
  __shared__ float sRedS[16][4];
  __shared__ unsigned short sVt[4][48][72];
  __shared__ float sO[4][16][48];

  f32x4 zf = {0.f,0.f,0.f,0.f};
  bf16x8 zero8 = {0,0,0,0,0,0,0,0};

  // ---- QK^T ----
  f32x4 accs[16];
  #pragma unroll
  for(int f=0;f<16;f++) accs[f] = zf;
  bf16x8 aq0, aq1;
  {
    const unsigned short* qp = qkvg + (long long)(i0 + l15)*3072 + h*48;
    aq0 = *(const bf16x8*)(qp + l4*8);
    aq1 = *(const bf16x8*)(qp + 32 + l4*8);
  }
  const int jbase = w * 256;
  #pragma unroll
  for(int f=0; f<16; f++){
    const int j = jbase + f*16 + l15;
    const unsigned short* kp = qkvg + (long long)j*3072 + 768 + h*48;
    bf16x8 bk0 = *(const bf16x8*)(kp + l4*8);
    bf16x8 bk1 = *(const bf16x8*)(kp + 32 + l4*8);
    if(l4 >= 2) bk1 = zero8;                 // zero k>=48 (pad B, A garbage*0)
    accs[f] = __builtin_amdgcn_mfma_f32_16x16x32_bf16(aq0, bk0, accs[f], 0,0,0);
    accs[f] = __builtin_amdgcn_mfma_f32_16x16x32_bf16(aq1, bk1, accs[f], 0,0,0);
  }
  // ---- scale + pair bias ----
  const float scale = 0.14433756729740643f;  // 1/sqrt(48)
  const unsigned short* pbh = pbias + ((long long)h << 20);
  #pragma unroll
  for(int f=0;f<16;f++){
    const int j = jbase + f*16 + l15;
    #pragma unroll
    for(int r=0;r<4;r++){
      const int i = i0 + l4*4 + r;
      accs[f][r] = accs[f][r]*scale + bf2f(pbh[((long long)i << 10) + j]);
    }
  }
  // ---- softmax (unnormalized) ----
  float pm[4];
  #pragma unroll
  for(int r=0;r<4;r++){
    float m = accs[0][r];
    #pragma unroll
    for(int f=1;f<16;f++) m = fmaxf(m, accs[f][r]);
    #pragma unroll
    for(int o=1;o<16;o<<=1) m = fmaxf(m, __shfl_xor(m, o));
    pm[r] = m;
  }
  if(l15 == 0){
    #pragma unroll
    for(int r=0;r<4;r++) sRedM[l4*4 + r][w] = pm[r];
  }
  __syncthreads();
  float rowm[4];
  #pragma unroll
  for(int r=0;r<4;r++){
    const int i = l4*4 + r;
    rowm[r] = fmaxf(fmaxf(sRedM[i][0], sRedM[i][1]), fmaxf(sRedM[i][2], sRedM[i][3]));
  }
  float psum[4] = {0.f,0.f,0.f,0.f};
  #pragma unroll
  for(int f=0;f<16;f++)
    #pragma unroll
    for(int r=0;r<4;r++){
      float p = __expf(accs[f][r] - rowm[r]);
      accs[f][r] = p;
      psum[r] += p;
    }
  #pragma unroll
  for(int r=0;r<4;r++)
    #pragma unroll
    for(int o=1;o<16;o<<=1) psum[r] += __shfl_xor(psum[r], o);
  if(l15 == 0){
    #pragma unroll
    for(int r=0;r<4;r++) sRedS[l4*4 + r][w] = psum[r];
  }
  #pragma unroll
  for(int f=0;f<16;f++)
    #pragma unroll
    for(int r=0;r<4;r++)
      sP[l4*4 + r][jbase + f*16 + l15] = f2bf(accs[f][r]);
  __syncthreads();

  // ---- PV ----
  f32x4 acco[3];
  #pragma unroll
  for(int n=0;n<3;n++) acco[n] = zf;
  for(int c=0; c<4; c++){
    const int jb = jbase + c*64;
    {
      const unsigned short* vp = qkvg + (long long)(jb + l)*3072 + 1536 + h*48;
      #pragma unroll
      for(int dg=0; dg<6; dg++){
        bf16x8 vv = *(const bf16x8*)(vp + dg*8);
        #pragma unroll
        for(int e=0;e<8;e++) sVt[w][dg*8 + e][l] = (unsigned short)vv[e];
      }
    }
    __syncthreads();
    #pragma unroll
    for(int kk=0; kk<2; kk++){
      bf16x8 pa = *(const bf16x8*)&sP[l15][jb + kk*32 + l4*8];
      #pragma unroll
      for(int n=0;n<3;n++){
        bf16x8 bv = *(const bf16x8*)&sVt[w][n*16 + l15][kk*32 + l4*8];
        acco[n] = __builtin_amdgcn_mfma_f32_16x16x32_bf16(pa, bv, acco[n], 0,0,0);
      }
    }
    __syncthreads();
  }
  #pragma unroll
  for(int n=0;n<3;n++)
    #pragma unroll
    for(int r=0;r<4;r++)
      sO[w][l4*4 + r][n*16 + l15] = acco[n][r];
  __syncthreads();
  // ---- epilogue: o/l * sigmoid(g) ----
  for(int t = tid; t < 768; t += 256){
    const int i = t / 48, d = t % 48;
    float o = sO[0][i][d] + sO[1][i][d] + sO[2][i][d] + sO[3][i][d];
    float lsum = sRedS[i][0] + sRedS[i][1] + sRedS[i][2] + sRedS[i][3];
    float gv = bf2f(qkvg[(long long)(i0 + i)*3072 + 2304 + h*48 + d]);
    go[(long long)(i0 + i)*768 + h*48 + d] = f2bf(sigf(gv) * (o / lsum));
  }
}

// ---------------------------------------------------------------------------
extern "C" void kernel_launch(void* const* d_in, const int* in_sizes, int n_in,
                              void* d_out, int out_size, void* d_ws, size_t ws_size,
                              hipStream_t stream){
  (void)in_sizes; (void)n_in; (void)out_size; (void)ws_size;
  const float* x    = (const float*)d_in[0];
  const float* sc   = (const float*)d_in[1];
  const float* pair = (const float*)d_in[2];
  const float* agw  = (const float*)d_in[3];
  const float* agb  = (const float*)d_in[4];
  const float* abw  = (const float*)d_in[5];
  const float* wq   = (const float*)d_in[6];
  const float* bq   = (const float*)d_in[7];
  const float* wk   = (const float*)d_in[8];
  const float* wv   = (const float*)d_in[9];
  const float* wb   = (const float*)d_in[10];
  const float* wg   = (const float*)d_in[11];
  const float* wo   = (const float*)d_in[12];
  const float* gtw  = (const float*)d_in[13];
  const float* gtb  = (const float*)d_in[14];
  const float* fgw  = (const float*)d_in[15];
  const float* fgb  = (const float*)d_in[16];
  const float* fbw  = (const float*)d_in[17];
  const float* fw1  = (const float*)d_in[18];
  const float* fw2  = (const float*)d_in[19];
  const float* fw3  = (const float*)d_in[20];
  const float* fgtw = (const float*)d_in[21];
  const float* fgtb = (const float*)d_in[22];
  float* out = (float*)d_out;
  char* ws = (char*)d_ws;

  unsigned short* SN   = (unsigned short*)(ws + OFF_SN);
  unsigned short* SC   = (unsigned short*)(ws + OFF_SC);
  float*          XA   = (float*)(ws + OFF_XA);
  unsigned short* W1   = (unsigned short*)(ws + OFF_W1);
  unsigned short* W2   = (unsigned short*)(ws + OFF_W2);
  unsigned short* W3   = (unsigned short*)(ws + OFF_W3);
  unsigned short* W4   = (unsigned short*)(ws + OFF_W4);
  unsigned short* W5   = (unsigned short*)(ws + OFF_W5);
  unsigned short* W6   = (unsigned short*)(ws + OFF_W6);
  float*          B1   = (float*)(ws + OFF_BIAS1);
  float*          BG   = (float*)(ws + OFF_BIASG);
  float*          BQ   = (float*)(ws + OFF_BIASQ);
  float*          G1   = (float*)(ws + OFF_G1);
  float*          GT   = (float*)(ws + OFF_GATES);
  unsigned short* A_   = (unsigned short*)(ws + OFF_A);
  unsigned short* F_   = (unsigned short*)(ws + OFF_F);
  unsigned short* QKVG = (unsigned short*)(ws + OFF_QKVG);
  float*          H12  = (float*)(ws + OFF_H12);
  unsigned short* HH   = (unsigned short*)(ws + OFF_HH);
  unsigned short* GO   = (unsigned short*)(ws + OFF_GO);
  float*          AP   = (float*)(ws + OFF_AP);
  unsigned short* PB   = (unsigned short*)(ws + OFF_PB);

  WJobs jobs;
  int ji = 0;
  auto setj = [&](const float* s, unsigned long long off, int K, int N){
    jobs.src[ji]=s; jobs.dst[ji]=off; jobs.K[ji]=K; jobs.N[ji]=N; ji++;
  };
  const unsigned long long W768 = 768ULL*768ULL*2ULL;
  setj(agw,  OFF_W1 + 0*W768, 768, 768);
  setj(abw,  OFF_W1 + 1*W768, 768, 768);
  setj(fgw,  OFF_W1 + 2*W768, 768, 768);
  setj(fbw,  OFF_W1 + 3*W768, 768, 768);
  setj(gtw,  OFF_W2 + 0*W768, 768, 768);
  setj(fgtw, OFF_W2 + 1*W768, 768, 768);
  setj(wq,   OFF_W3 + 0*W768, 768, 768);
  setj(wk,   OFF_W3 + 1*W768, 768, 768);
  setj(wv,   OFF_W3 + 2*W768, 768, 768);
  setj(wg,   OFF_W3 + 3*W768, 768, 768);
  setj(fw1,  OFF_W4 + 0,               768, 1536);
  setj(fw2,  OFF_W4 + 1536ULL*768*2,   768, 1536);
  setj(fw3,  OFF_W5, 1536, 768);
  setj(wo,   OFF_W6, 768, 768);

  transpose_cast_kernel<<<dim3(48,48,14), dim3(32,8), 0, stream>>>(jobs, ws);
  build_bias_kernel<<<12, 256, 0, stream>>>(agb, bq, gtb, fgtb, fgb, B1, BG, BQ);
  ln_kernel<<<1024, 256, 0, stream>>>(x, sc, SN, SC, XA);
  pair_bias_kernel<<<16384, 256, 0, stream>>>(pair, wb, PB);

  // G1: sn @ [ag|ab|fg|fb]  -> f32 (+bias)
  gemm_kernel<0><<<dim3(16,24), 256, 0, stream>>>(SN, W1, 1024, 3072, 768,
      B1, G1, nullptr, nullptr, nullptr, nullptr, 0);
  // gates: sigmoid(sc @ [attn_gate|ff_gate] + b) -> f32
  gemm_kernel<1><<<dim3(16,12), 256, 0, stream>>>(SC, W2, 1024, 1536, 768,
      BG, GT, nullptr, nullptr, nullptr, nullptr, 0);
  // adaLN combine -> a, f (bf16)
  ew1_kernel<<<dim3(1024,3), 256, 0, stream>>>(G1, XA, A_, F_);
  // qkvg = a @ [wq|wk|wv|wg] + [bq|0|0|0] -> bf16
  gemm_kernel<2><<<dim3(16,24), 256, 0, stream>>>(A_, W3, 1024, 3072, 768,
      BQ, nullptr, QKVG, nullptr, nullptr, nullptr, 0);
  // h12 = f @ [w1|w2] -> f32
  gemm_kernel<0><<<dim3(16,24), 256, 0, stream>>>(F_, W4, 1024, 3072, 768,
      nullptr, H12, nullptr, nullptr, nullptr, nullptr, 0);
  // hh = silu(h1)*h2 -> bf16
  ew2_kernel<<<dim3(1024,6), 256, 0, stream>>>(H12, HH);
  // attention -> go = sigmoid(g)*o (bf16)
  attn_kernel<<<1024, 256, 0, stream>>>(QKVG, PB, GO);
  // AP = attn_gate * (go @ wo)
  gemm_kernel<3><<<dim3(16,6), 256, 0, stream>>>(GO, W6, 1024, 768, 768,
      nullptr, AP, nullptr, nullptr, nullptr, GT, 0);
  // out = x + AP + ff_gate * (hh @ w3)
  gemm_kernel<4><<<dim3(16,6), 256, 0, stream>>>(HH, W5, 1024, 768, 1536,
      nullptr, out, nullptr, x, AP, GT, 768);
}